// Round 6
// baseline (464.427 us; speedup 1.0000x reference)
//
#include <hip/hip_runtime.h>
#include <stdint.h>

// MPS classifier forward, MI355X.
//   k1  : (127,2) blocks, 2 round-1 basis products per block (A-row split)
//   k2f : (63,8) blocks — REPLACES k1b+k1c+k2c (r6). Factorization:
//         sum_pq c1p c2q (T1p@T2q) = (sum_p c1p T1p)@(sum_q c2q T2q), so M0
//         comes straight from T: per block, register-cache the thread's slice
//         of all 8 bases (16 uint4, STATIC indices — r2's spill was a runtime-
//         branched aggregate), then per batch: VALU-combine into 2 LDS bufs ->
//         128^3 MFMA -> norm from accumulator (log||A@B|| == folded r1+r2 logs,
//         same quantity k2ns's Gram produced) -> scaled bounce -> copy_out.
//         Kills 99 MB of TT round-trips + k2c's 49 us VALU combine.
//         r4 lesson: MFMA operands from LDS, never scattered global.
//   k2ns: 64 blocks, special chain r1+r2 only (Gram/cbuf branch deleted).
//   round2x: TWO pairwise rounds fused, folded logs (r5: logs only ever
//         SUMMED -> mid normalizations fold into final log; 1 reduction/task),
//         2-buffer schedule, 71 KB LDS.
//   r7f : R7 + R8 + logits fused, folded logs, 1 reduction.

typedef unsigned short u16;
typedef __attribute__((ext_vector_type(8))) short short8;
typedef __attribute__((ext_vector_type(4))) float f32x4;

#define HP 136  // LDS row stride in bf16: 272 B, 16B-aligned, 2-way-bank-free

__device__ __forceinline__ u16 f2b(float f) {
  uint32_t u = __builtin_bit_cast(uint32_t, f);
  u += 0x7FFFu + ((u >> 16) & 1u);
  return (u16)(u >> 16);
}
__device__ __forceinline__ float b2f(u16 b) {
  uint32_t u = ((uint32_t)b) << 16;
  return __builtin_bit_cast(float, u);
}

struct AccW { f32x4 t[2][2]; };  // 16-wave config: 32x32 wave tile

// 1024-thread (16-wave) 128x128x128 from LDS. A: [m][k], B: [n][k], stride HP.
__device__ __forceinline__ void mfma_w16(const u16* Alds, const u16* Blds,
                                         AccW& acc) {
  const int tid = threadIdx.x;
  const int wid = tid >> 6, lane = tid & 63;
  const int wm = (wid >> 2) * 32, wn = (wid & 3) * 32;
  const int l16 = lane & 15, quad = lane >> 4;
#pragma unroll
  for (int tm = 0; tm < 2; tm++)
#pragma unroll
    for (int tn = 0; tn < 2; tn++)
      acc.t[tm][tn] = (f32x4){0.f, 0.f, 0.f, 0.f};
#pragma unroll
  for (int kk = 0; kk < 128; kk += 32) {
    short8 af[2], bf[2];
#pragma unroll
    for (int t = 0; t < 2; t++) {
      af[t] = *(const short8*)(Alds + (wm + t * 16 + l16) * HP + kk + quad * 8);
      bf[t] = *(const short8*)(Blds + (wn + t * 16 + l16) * HP + kk + quad * 8);
    }
#pragma unroll
    for (int tm = 0; tm < 2; tm++)
#pragma unroll
      for (int tn = 0; tn < 2; tn++)
        acc.t[tm][tn] = __builtin_amdgcn_mfma_f32_16x16x32_bf16(
            af[tm], bf[tn], acc.t[tm][tn], 0, 0, 0);
  }
}

__device__ __forceinline__ float acc_sumsq(const AccW& acc) {
  float ss = 0.f;
#pragma unroll
  for (int tm = 0; tm < 2; tm++)
#pragma unroll
    for (int tn = 0; tn < 2; tn++)
#pragma unroll
      for (int i = 0; i < 4; i++) {
        float v = acc.t[tm][tn][i];
        ss += v * v;
      }
  return ss;
}

// Write acc into bounce LDS (stride HP). transposed -> buffer row = col index.
// C/D layout (m89): row = quad*4 + reg, col = lane&15 per 16x16 tile.
__device__ __forceinline__ void bounce_store(u16* Lb, const AccW& acc, float scale,
                                             bool transposed) {
  const int tid = threadIdx.x;
  const int wid = tid >> 6, lane = tid & 63;
  const int wm = (wid >> 2) * 32, wn = (wid & 3) * 32;
  const int l16 = lane & 15, quad = lane >> 4;
#pragma unroll
  for (int tm = 0; tm < 2; tm++)
#pragma unroll
    for (int tn = 0; tn < 2; tn++)
#pragma unroll
      for (int i = 0; i < 4; i++) {
        int r = wm + tm * 16 + quad * 4 + i;
        int c = wn + tn * 16 + l16;
        int key = transposed ? c : r, sec = transposed ? r : c;
        Lb[key * HP + sec] = f2b(acc.t[tm][tn][i] * scale);
      }
}

// 1024 threads: copy bounce LDS -> global, fully coalesced uint4.
__device__ __forceinline__ void copy_out(const u16* Lb, u16* out) {
  const int tid = threadIdx.x;
#pragma unroll
  for (int i = 0; i < 2; i++) {
    int g8 = tid + i * 1024;  // 0..2047 uint4 units
    int row = g8 >> 4, c8 = g8 & 15;
    *(uint4*)(out + g8 * 8) = *(const uint4*)(Lb + row * HP + c8 * 8);
  }
}

// 1024 threads: global matrix (32 KB) -> LDS (stride HP), coalesced uint4.
__device__ __forceinline__ void loadM(u16* Lb, const u16* __restrict__ src) {
  const int tid = threadIdx.x;
#pragma unroll
  for (int i = 0; i < 2; i++) {
    int g8 = tid + i * 1024;
    int r = g8 >> 4, c8 = g8 & 15;
    *(uint4*)(Lb + r * HP + c8 * 8) = *(const uint4*)(src + g8 * 8);
  }
}

// legacy 3-barrier block reduction (k2ns, 2 waves)
__device__ __forceinline__ float block_sum(float v, float* red, int nw) {
#pragma unroll
  for (int off = 32; off > 0; off >>= 1) v += __shfl_down(v, off);
  int wid = threadIdx.x >> 6;
  if ((threadIdx.x & 63) == 0) red[wid] = v;
  __syncthreads();
  if (threadIdx.x == 0) {
    float s = 0.f;
    for (int w = 0; w < nw; w++) s += red[w];
    red[0] = s;
  }
  __syncthreads();
  float s = red[0];
  __syncthreads();
  return s;
}

// lean 1-barrier 16-wave reduction; every call site has >=2 barriers between
// successive uses of red -> WAR-safe.
__device__ __forceinline__ float bsum16(float v, float* red) {
#pragma unroll
  for (int off = 32; off > 0; off >>= 1) v += __shfl_down(v, off);
  if ((threadIdx.x & 63) == 0) red[threadIdx.x >> 6] = v;
  __syncthreads();
  float s = 0.f;
#pragma unroll
  for (int w = 0; w < 16; w++) s += red[w];
  return s;
}

// ---------------- k1: two round-1 basis products per block (A-row split) -----
__global__ __launch_bounds__(1024) void k1(const float* __restrict__ cores,
                                           u16* __restrict__ T) {
  __shared__ u16 Ald[128 * HP], B0[128 * HP], B1[128 * HP];
  const int j = blockIdx.x;   // 0..126 -> cores (2j+1, 2j+2)
  const int p = blockIdx.y;   // 0: A0 row (coeffs 1,b), 1: A1 row (coeffs a,ab)
  const float* c1 = cores + (size_t)(2 * j + 1) * 32768;
  const float* c2 = cores + (size_t)(2 * j + 2) * 32768;
  const int tid = threadIdx.x;
#pragma unroll 4
  for (int i = 0; i < 16; i++) {
    int lh = tid + i * 1024;
    int l = lh >> 7, h = lh & 127;
    float a0 = c1[(l * 2 + 0) * 128 + h];
    float av = p ? (c1[(l * 2 + 1) * 128 + h] - a0) : a0;
    Ald[l * HP + h] = f2b(av);
    float b0 = c2[(l * 2 + 0) * 128 + h];
    float b1 = c2[(l * 2 + 1) * 128 + h];
    B0[h * HP + l] = f2b(b0);  // B basis transposed in LDS
    B1[h * HP + l] = f2b(b1 - b0);
  }
  __syncthreads();
  const bool tr = (j % 2) == 0;  // even -> consumed as B operand -> store C^T
  u16* Tj = T + ((size_t)j * 4 + p * 2) * 16384;
  AccW q0, q1;
  mfma_w16(Ald, B0, q0);
  mfma_w16(Ald, B1, q1);
  __syncthreads();  // A dead -> bounce
  bounce_store(Ald, q0, 1.f, tr); __syncthreads();
  copy_out(Ald, Tj + 0 * 16384);  __syncthreads();
  bounce_store(Ald, q1, 1.f, tr); __syncthreads();
  copy_out(Ald, Tj + 1 * 16384);
}

// ---------------- k2f: combine bases + round-2 matmul + norm -> M0 ----------
// grid (63, 8): block (j2, g) handles batches b = g*8..g*8+7 for r2 pair j2.
// A_b = sum_p c1[p] T[(2j2+1)*4+p]  (row-major flat, odd k1-block)
// B_b = sum_q c2[q] T[(2j2+2)*4+q]  (transposed-stored flat = [n][k] ready)
// M0[b][j2] = (A_b @ B_b)/n, logs[1+j2] = log n  (folded r1+r2 log, same
// quantity the old Gram path produced). Bases register-cached: 16 uint4 =
// 64 VGPR, static indices only. LDS 2 buffers = 70 KB.
__global__ __launch_bounds__(1024, 4) void k2f(const u16* __restrict__ T,
                                               const float* __restrict__ x,
                                               u16* __restrict__ M0,
                                               float* __restrict__ logs) {
  __shared__ u16 L0[128 * HP], L1[128 * HP];
  __shared__ float red[16];
  const int j2 = blockIdx.x, g = blockIdx.y, tid = threadIdx.x;
  const u16* TA = T + ((size_t)(2 * j2 + 1) * 4) * 16384;
  const u16* TB = T + ((size_t)(2 * j2 + 2) * 4) * 16384;
  // register-cache this thread's slice of all 8 bases (static indexing)
  uint4 rA[2][4], rB[2][4];
#pragma unroll
  for (int i = 0; i < 2; i++) {
    int gg = (tid + i * 1024) * 8;
#pragma unroll
    for (int p = 0; p < 4; p++) {
      rA[i][p] = *(const uint4*)(TA + (size_t)p * 16384 + gg);
      rB[i][p] = *(const uint4*)(TB + (size_t)p * 16384 + gg);
    }
  }
  for (int bb = 0; bb < 8; bb++) {
    const int b = g * 8 + bb;
    const float* xb = x + b * 256;
    float a1 = xb[4 * j2 + 4], b1 = xb[4 * j2 + 5];
    float a2 = xb[4 * j2 + 6], b2 = xb[4 * j2 + 7];
    float ab1 = a1 * b1, ab2 = a2 * b2;
#pragma unroll
    for (int i = 0; i < 2; i++) {
      int gg = tid + i * 1024;
      int row = gg >> 4, c8 = gg & 15;
      union { uint4 v; u16 s[8]; } q0, q1, q2, q3, oA, oB;
      q0.v = rA[i][0]; q1.v = rA[i][1]; q2.v = rA[i][2]; q3.v = rA[i][3];
#pragma unroll
      for (int e = 0; e < 8; e++) {
        float v = b2f(q0.s[e]) + b1 * b2f(q1.s[e]) + a1 * b2f(q2.s[e]) +
                  ab1 * b2f(q3.s[e]);
        oA.s[e] = f2b(v);
      }
      q0.v = rB[i][0]; q1.v = rB[i][1]; q2.v = rB[i][2]; q3.v = rB[i][3];
#pragma unroll
      for (int e = 0; e < 8; e++) {
        float v = b2f(q0.s[e]) + b2 * b2f(q1.s[e]) + a2 * b2f(q2.s[e]) +
                  ab2 * b2f(q3.s[e]);
        oB.s[e] = f2b(v);
      }
      *(uint4*)(L0 + row * HP + c8 * 8) = oA.v;
      *(uint4*)(L1 + row * HP + c8 * 8) = oB.v;
    }
    __syncthreads();
    AccW acc;
    mfma_w16(L0, L1, acc);
    float t = bsum16(acc_sumsq(acc), red);  // barrier fences MFMA LDS reads
    float n = fmaxf(sqrtf(t), 1e-12f);
    if (tid == 0) logs[b * 127 + 1 + j2] = logf(n);
    bounce_store(L0, acc, 1.f / n, (j2 % 2) == 0);
    __syncthreads();
    copy_out(L0, M0 + ((size_t)b * 63 + j2) * 16384);
    __syncthreads();  // L0/L1 free for next batch
  }
}

// ---------------- k2ns: special chain rounds 1+2 (64 blocks) ----------------
__global__ __launch_bounds__(128) void k2ns(const float* __restrict__ x,
                                            const float* __restrict__ core0,
                                            const float* __restrict__ cores,
                                            const u16* __restrict__ T,
                                            float* __restrict__ sA,
                                            float* __restrict__ logs) {
  __shared__ float svec[128];
  __shared__ float red[8];
  const int b = blockIdx.x, tid = threadIdx.x;
  const float* xb = x + b * 256;
  float x0 = xb[0], x1 = xb[1];
  svec[tid] = core0[tid] * (1.f - x0) + core0[128 + tid] * x0;
  __syncthreads();
  float acc1 = 0.f;
  for (int k = 0; k < 128; k++) {
    float m0 = cores[(k * 2 + 0) * 128 + tid];
    float m1 = cores[(k * 2 + 1) * 128 + tid];
    acc1 += svec[k] * (m0 + x1 * (m1 - m0));
  }
  float tot = block_sum(acc1 * acc1, red, 2);
  float n1 = fmaxf(sqrtf(tot), 1e-12f);
  float ln = logf(n1);
  svec[tid] = acc1 / n1;
  __syncthreads();
  float a = xb[2], bb = xb[3], ab = a * bb;
  float acc2 = 0.f;
  for (int k8 = 0; k8 < 16; k8++) {
    union { uint4 v; u16 s[8]; } q00, q01, q10, q11;
    q00.v = *(const uint4*)(T + tid * 128 + k8 * 8);
    q01.v = *(const uint4*)(T + 16384 + tid * 128 + k8 * 8);
    q10.v = *(const uint4*)(T + 32768 + tid * 128 + k8 * 8);
    q11.v = *(const uint4*)(T + 49152 + tid * 128 + k8 * 8);
#pragma unroll
    for (int e = 0; e < 8; e++) {
      float pk = b2f(q00.s[e]) + a * b2f(q10.s[e]) + bb * b2f(q01.s[e]) +
                 ab * b2f(q11.s[e]);
      acc2 += svec[k8 * 8 + e] * pk;
    }
  }
  float tot2 = block_sum(acc2 * acc2, red, 2);
  float n2 = fmaxf(sqrtf(tot2), 1e-12f);
  sA[b * 128 + tid] = acc2 / n2;
  if (tid == 0) logs[b * 127 + 0] = ln + logf(n2);
}

// ---------------- round2x: TWO rounds fused, 2-buffer, folded logs -----------
// grid (1 + count_out, 64).  p>=1 (m=p-1):
//   stage In[4m+3],In[4m+4] -> a1 = mm; restage In[4m+5],In[4m+6] -> a2 = mm
//   (a1 lives in VGPRs across the restage); bounce a1->L0 (row-major, scale 1),
//   a2->L1 (transposed, scale 1); a3 = L0@L1; n3 = ||a3|| is the ONLY
//   reduction; mid log slots <- 0. bounce a3/n3 -> L0 (parity); copy_out.
// p==0: special chain, same folding.
__global__ __launch_bounds__(1024, 4) void round2x(const u16* __restrict__ In,
                                                   u16* __restrict__ Out,
                                                   const float* __restrict__ sIn,
                                                   float* __restrict__ sOut,
                                                   float* __restrict__ logs,
                                                   int count_in, int count_out,
                                                   int slot0, int slot1) {
  __shared__ u16 L0[128 * HP], L1[128 * HP];
  __shared__ float svf[256];
  __shared__ float red[16];
  const int b = blockIdx.y, p = blockIdx.x, tid = threadIdx.x;
  const u16* base = In + (size_t)b * count_in * 16384;
  if (p == 0) {
    if (tid < 128) svf[tid] = sIn[b * 128 + tid];
    loadM(L0, base + 1 * 16384);   // In[1]: odd -> row-major -> A
    loadM(L1, base + 2 * 16384);   // In[2]: even -> transposed -> B
    __syncthreads();
    // acc0 = svec @ In[0] (unnormalized); In[0] stored transposed [h][l]
    float acc0 = 0.f;
    if (tid < 128) {
      for (int k8 = 0; k8 < 16; k8++) {
        union { uint4 v; u16 s[8]; } q;
        q.v = *(const uint4*)(base + tid * 128 + k8 * 8);
#pragma unroll
        for (int e = 0; e < 8; e++) acc0 += svf[k8 * 8 + e] * b2f(q.s[e]);
      }
    }
    AccW accq;
    mfma_w16(L0, L1, accq);        // Q = In[1]@In[2], unnormalized
    __syncthreads();               // all reads of L0/L1 done
    bounce_store(L0, accq, 1.f, true);  // Qt[c][r]
    if (tid < 128) svf[128 + tid] = acc0;
    if (tid == 0) {
      logs[b * 127 + slot0] = 0.f;
      logs[b * 127 + slot0 + 1] = 0.f;
    }
    __syncthreads();
    // svec'' = normalize((svec@In0) @ Q); single log absorbs all three norms
    float acc2 = 0.f;
    if (tid < 128) {
      for (int l = 0; l < 128; l++) acc2 += svf[128 + l] * b2f(L0[tid * HP + l]);
    }
    float t2 = bsum16((tid < 128) ? acc2 * acc2 : 0.f, red);
    float n2 = fmaxf(sqrtf(t2), 1e-12f);
    if (tid == 0) logs[b * 127 + slot1] = logf(n2);
    if (tid < 128) sOut[b * 128 + tid] = acc2 / n2;
  } else {
    const int m = p - 1;
    loadM(L0, base + (size_t)(4 * m + 3) * 16384);
    loadM(L1, base + (size_t)(4 * m + 4) * 16384);
    __syncthreads();
    AccW a1;
    mfma_w16(L0, L1, a1);
    __syncthreads();               // all reads done -> restage
    loadM(L0, base + (size_t)(4 * m + 5) * 16384);
    loadM(L1, base + (size_t)(4 * m + 6) * 16384);
    __syncthreads();
    AccW a2;
    mfma_w16(L0, L1, a2);
    __syncthreads();               // all reads done -> bounce over operands
    bounce_store(L0, a1, 1.f, false);  // mid 2m+1 (odd) -> A row-major
    bounce_store(L1, a2, 1.f, true);   // mid 2m+2 (even) -> B transposed
    if (tid == 0) {                    // folded logs: zero the mid slots
      logs[b * 127 + slot0 + 2 + 2 * m] = 0.f;
      logs[b * 127 + slot0 + 3 + 2 * m] = 0.f;
    }
    __syncthreads();
    AccW a3;
    mfma_w16(L0, L1, a3);
    float t3 = bsum16(acc_sumsq(a3), red);  // its barrier also fences L0 reads
    float n3 = fmaxf(sqrtf(t3), 1e-12f);
    if (tid == 0) logs[b * 127 + slot1 + 1 + m] = logf(n3);
    bounce_store(L0, a3, 1.f / n3, (m % 2) == 0);
    __syncthreads();
    copy_out(L0, Out + ((size_t)b * count_out + m) * 16384);
  }
}

// ---------------- r7f: R7 + R8 + logits; folded logs -> 1 reduction ----------
__global__ __launch_bounds__(1024, 8) void r7f(const u16* __restrict__ In,
                                               const float* __restrict__ sIn,
                                               const float* __restrict__ logs,
                                               const float* __restrict__ cls,
                                               float* __restrict__ out) {
  __shared__ u16 Ald[128 * HP], Bld[128 * HP];
  __shared__ float svec[128], ovec[128], red[16];
  const int b = blockIdx.x, tid = threadIdx.x;
  if (tid < 128) svec[tid] = sIn[b * 128 + tid];
  loadM(Ald, In + ((size_t)b * 3 + 1) * 16384);   // row-major
  loadM(Bld, In + ((size_t)b * 3 + 2) * 16384);   // transposed
  __syncthreads();
  AccW acc;
  mfma_w16(Ald, Bld, acc);   // C = In1@In2, unnormalized
  // acc0 = svec @ In0 (unnormalized); In0 transposed layout
  const u16* M0p = In + (size_t)b * 3 * 16384;
  float acc0 = 0.f;
  if (tid < 128) {
    for (int k8 = 0; k8 < 16; k8++) {
      union { uint4 v; u16 s[8]; } q;
      q.v = *(const uint4*)(M0p + tid * 128 + k8 * 8);
#pragma unroll
      for (int e = 0; e < 8; e++) acc0 += svec[k8 * 8 + e] * b2f(q.s[e]);
    }
  }
  __syncthreads();  // all Ald/Bld reads done
  bounce_store(Ald, acc, 1.f, true);  // C^T [c][r]
  if (tid < 128) ovec[tid] = acc0;
  __syncthreads();
  // res = (svec@In0) @ C; single log absorbs n0, n1, n2
  float acc2 = 0.f;
  if (tid < 128) {
    for (int r = 0; r < 128; r++) acc2 += ovec[r] * b2f(Ald[tid * HP + r]);
  }
  float tot = bsum16((tid < 128) ? acc2 * acc2 : 0.f, red);
  float n = fmaxf(sqrtf(tot), 1e-12f);
  float lg = logf(n);
  if (tid < 128) svec[tid] = acc2 / n;
  __syncthreads();
  if (tid < 10) {
    float a = 0.f;
    for (int h = 0; h < 128; h++) a += svec[h] * cls[tid * 128 + h];
    float L = lg;
    for (int i = 0; i < 124; i++) L += logs[b * 127 + i];
    out[b * 10 + tid] = a + L;
  }
}

extern "C" void kernel_launch(void* const* d_in, const int* in_sizes, int n_in,
                              void* d_out, int out_size, void* d_ws, size_t ws_size,
                              hipStream_t stream) {
  (void)in_sizes; (void)n_in; (void)out_size; (void)ws_size;
  const float* x     = (const float*)d_in[0];  // (64,256)
  const float* core0 = (const float*)d_in[1];  // (1,2,128)
  const float* cores = (const float*)d_in[2];  // (255,128,2,128)
  const float* cls   = (const float*)d_in[3];  // (10,128)
  float* out = (float*)d_out;
  char* ws = (char*)d_ws;

  // Region A (65 MB): early = T (16.6 MB); later reused as M2 (T dead after
  // k2f/k2ns). M0 at ws+SZ_A.
  constexpr size_t SZ_A  = (size_t)64 * 31 * 16384 * 2;   //  65,011,712
  constexpr size_t SZ_M0 = (size_t)64 * 63 * 16384 * 2;   // 132,120,576

  u16*   T    = (u16*)(ws);
  u16*   M2   = (u16*)(ws);            // aliases T after k2f+k2ns complete
  u16*   M0   = (u16*)(ws + SZ_A);
  char*  tail0 = ws + SZ_A + SZ_M0;
  float* sA   = (float*)(tail0 + 262144 + 262144);
  float* sB   = (float*)(tail0 + 262144 + 262144 + 32768);
  float* logs = (float*)(tail0 + 262144 + 262144 + 65536);

  k1  <<<dim3(127, 2), 1024, 0, stream>>>(cores, T);
  k2f <<<dim3(63, 8), 1024, 0, stream>>>(T, x, M0, logs);
  k2ns<<<dim3(64), 128, 0, stream>>>(x, core0, cores, T, sA, logs);
  // log slots: 0 special(r1+r2), 1..63 pairs(r1+r2, from k2f);
  //   R3R4: 64,65 <- 0, 66..95 <- 0 (mids), 96 sp-total, 97..111 out pairs;
  //   R5R6: 112,113 <- 0, 114..119 <- 0, 120 sp-total, 121..123 out;
  //   r7f folds its three logs into one local value.
  round2x<<<dim3(16, 64), 1024, 0, stream>>>(M0, M2, sA, sB, logs, 63, 15, 64, 96);
  round2x<<<dim3(4, 64), 1024, 0, stream>>>(M2, M0, sB, sA, logs, 15, 3, 112, 120);
  r7f  <<<dim3(64), 1024, 0, stream>>>(M0, sA, logs, cls, out);
}

// Round 7
// 242.123 us; speedup vs baseline: 1.9181x; 1.9181x over previous
//
#include <hip/hip_runtime.h>
#include <stdint.h>

// MPS classifier forward, MI355X.
//   k1  : (127,2) blocks, 2 round-1 basis products per block (A-row split)
//   k1b : (16,63) blocks, round-2 basis TT_t = T1_p @ T2_q (LDS-staged; r4:
//         never feed MFMA from scattered global — 84.6 vs 49.4 us)
//   k1c : (63,4) blocks, Gram partials over K-chunks
//   k2ns: 127 blocks: bx<63 -> coeffs/norms/logs; bx>=63 -> special chain r1+r2
//   k2c : (32,63) combine M0 = sum_t c'_t TT_t; 2 elems/thread (r0-proven 43us;
//         r5's 4-elem (16,63) was 49us — fewer blocks hurt latency hiding).
//         RULES: (1) every TT element read by EXACTLY ONE block; (2) VGPR cap
//         512/minw; (3) block-uniform coeffs via SGPRs (s_load), not LDS.
//         HARD RULE (r2 + r6, confirmed twice): any multi-uint4 per-thread
//         aggregate held live across __syncthreads()/MFMA in a 16-wave block
//         SPILLS (allocator targets 64 VGPR); static indexing does NOT save it.
//   round2x: TWO pairwise rounds fused, folded logs (r5: logs only ever
//         SUMMED -> mid normalizations fold into final log; 1 reduction/task),
//         2-buffer schedule, 71 KB LDS.
//   r7f : R7 + R8 + logits fused, folded logs, 1 reduction.

typedef unsigned short u16;
typedef __attribute__((ext_vector_type(8))) short short8;
typedef __attribute__((ext_vector_type(4))) float f32x4;

#define HP 136  // LDS row stride in bf16: 272 B, 16B-aligned, 2-way-bank-free

__device__ __forceinline__ u16 f2b(float f) {
  uint32_t u = __builtin_bit_cast(uint32_t, f);
  u += 0x7FFFu + ((u >> 16) & 1u);
  return (u16)(u >> 16);
}
__device__ __forceinline__ float b2f(u16 b) {
  uint32_t u = ((uint32_t)b) << 16;
  return __builtin_bit_cast(float, u);
}

struct AccW { f32x4 t[2][2]; };  // 16-wave config: 32x32 wave tile

// 1024-thread (16-wave) 128x128x128 from LDS. A: [m][k], B: [n][k], stride HP.
__device__ __forceinline__ void mfma_w16(const u16* Alds, const u16* Blds,
                                         AccW& acc) {
  const int tid = threadIdx.x;
  const int wid = tid >> 6, lane = tid & 63;
  const int wm = (wid >> 2) * 32, wn = (wid & 3) * 32;
  const int l16 = lane & 15, quad = lane >> 4;
#pragma unroll
  for (int tm = 0; tm < 2; tm++)
#pragma unroll
    for (int tn = 0; tn < 2; tn++)
      acc.t[tm][tn] = (f32x4){0.f, 0.f, 0.f, 0.f};
#pragma unroll
  for (int kk = 0; kk < 128; kk += 32) {
    short8 af[2], bf[2];
#pragma unroll
    for (int t = 0; t < 2; t++) {
      af[t] = *(const short8*)(Alds + (wm + t * 16 + l16) * HP + kk + quad * 8);
      bf[t] = *(const short8*)(Blds + (wn + t * 16 + l16) * HP + kk + quad * 8);
    }
#pragma unroll
    for (int tm = 0; tm < 2; tm++)
#pragma unroll
      for (int tn = 0; tn < 2; tn++)
        acc.t[tm][tn] = __builtin_amdgcn_mfma_f32_16x16x32_bf16(
            af[tm], bf[tn], acc.t[tm][tn], 0, 0, 0);
  }
}

__device__ __forceinline__ float acc_sumsq(const AccW& acc) {
  float ss = 0.f;
#pragma unroll
  for (int tm = 0; tm < 2; tm++)
#pragma unroll
    for (int tn = 0; tn < 2; tn++)
#pragma unroll
      for (int i = 0; i < 4; i++) {
        float v = acc.t[tm][tn][i];
        ss += v * v;
      }
  return ss;
}

// Write acc into bounce LDS (stride HP). transposed -> buffer row = col index.
// C/D layout (m89): row = quad*4 + reg, col = lane&15 per 16x16 tile.
__device__ __forceinline__ void bounce_store(u16* Lb, const AccW& acc, float scale,
                                             bool transposed) {
  const int tid = threadIdx.x;
  const int wid = tid >> 6, lane = tid & 63;
  const int wm = (wid >> 2) * 32, wn = (wid & 3) * 32;
  const int l16 = lane & 15, quad = lane >> 4;
#pragma unroll
  for (int tm = 0; tm < 2; tm++)
#pragma unroll
    for (int tn = 0; tn < 2; tn++)
#pragma unroll
      for (int i = 0; i < 4; i++) {
        int r = wm + tm * 16 + quad * 4 + i;
        int c = wn + tn * 16 + l16;
        int key = transposed ? c : r, sec = transposed ? r : c;
        Lb[key * HP + sec] = f2b(acc.t[tm][tn][i] * scale);
      }
}

// 1024 threads: copy bounce LDS -> global, fully coalesced uint4.
__device__ __forceinline__ void copy_out(const u16* Lb, u16* out) {
  const int tid = threadIdx.x;
#pragma unroll
  for (int i = 0; i < 2; i++) {
    int g8 = tid + i * 1024;  // 0..2047 uint4 units
    int row = g8 >> 4, c8 = g8 & 15;
    *(uint4*)(out + g8 * 8) = *(const uint4*)(Lb + row * HP + c8 * 8);
  }
}

// 1024 threads: global matrix (32 KB) -> LDS (stride HP), coalesced uint4.
__device__ __forceinline__ void loadM(u16* Lb, const u16* __restrict__ src) {
  const int tid = threadIdx.x;
#pragma unroll
  for (int i = 0; i < 2; i++) {
    int g8 = tid + i * 1024;
    int r = g8 >> 4, c8 = g8 & 15;
    *(uint4*)(Lb + r * HP + c8 * 8) = *(const uint4*)(src + g8 * 8);
  }
}

// legacy 3-barrier block reduction (k2ns, 2 waves)
__device__ __forceinline__ float block_sum(float v, float* red, int nw) {
#pragma unroll
  for (int off = 32; off > 0; off >>= 1) v += __shfl_down(v, off);
  int wid = threadIdx.x >> 6;
  if ((threadIdx.x & 63) == 0) red[wid] = v;
  __syncthreads();
  if (threadIdx.x == 0) {
    float s = 0.f;
    for (int w = 0; w < nw; w++) s += red[w];
    red[0] = s;
  }
  __syncthreads();
  float s = red[0];
  __syncthreads();
  return s;
}

// lean 1-barrier 16-wave reduction; every call site has >=2 barriers between
// successive uses of red -> WAR-safe.
__device__ __forceinline__ float bsum16(float v, float* red) {
#pragma unroll
  for (int off = 32; off > 0; off >>= 1) v += __shfl_down(v, off);
  if ((threadIdx.x & 63) == 0) red[threadIdx.x >> 6] = v;
  __syncthreads();
  float s = 0.f;
#pragma unroll
  for (int w = 0; w < 16; w++) s += red[w];
  return s;
}

// ---------------- k1: two round-1 basis products per block (A-row split) -----
__global__ __launch_bounds__(1024) void k1(const float* __restrict__ cores,
                                           u16* __restrict__ T) {
  __shared__ u16 Ald[128 * HP], B0[128 * HP], B1[128 * HP];
  const int j = blockIdx.x;   // 0..126 -> cores (2j+1, 2j+2)
  const int p = blockIdx.y;   // 0: A0 row (coeffs 1,b), 1: A1 row (coeffs a,ab)
  const float* c1 = cores + (size_t)(2 * j + 1) * 32768;
  const float* c2 = cores + (size_t)(2 * j + 2) * 32768;
  const int tid = threadIdx.x;
#pragma unroll 4
  for (int i = 0; i < 16; i++) {
    int lh = tid + i * 1024;
    int l = lh >> 7, h = lh & 127;
    float a0 = c1[(l * 2 + 0) * 128 + h];
    float av = p ? (c1[(l * 2 + 1) * 128 + h] - a0) : a0;
    Ald[l * HP + h] = f2b(av);
    float b0 = c2[(l * 2 + 0) * 128 + h];
    float b1 = c2[(l * 2 + 1) * 128 + h];
    B0[h * HP + l] = f2b(b0);  // B basis transposed in LDS
    B1[h * HP + l] = f2b(b1 - b0);
  }
  __syncthreads();
  const bool tr = (j % 2) == 0;  // even -> consumed as B operand -> store C^T
  u16* Tj = T + ((size_t)j * 4 + p * 2) * 16384;
  AccW q0, q1;
  mfma_w16(Ald, B0, q0);
  mfma_w16(Ald, B1, q1);
  __syncthreads();  // A dead -> bounce
  bounce_store(Ald, q0, 1.f, tr); __syncthreads();
  copy_out(Ald, Tj + 0 * 16384);  __syncthreads();
  bounce_store(Ald, q1, 1.f, tr); __syncthreads();
  copy_out(Ald, Tj + 1 * 16384);
}

// ---------------- k1b: round-2 basis TT_t = T1_p @ T2_q (staged, proven) -----
__global__ __launch_bounds__(1024, 8) void k1b(const u16* __restrict__ T,
                                               u16* __restrict__ TT) {
  __shared__ u16 Ald[128 * HP], Bld[128 * HP];
  const int t = blockIdx.x;   // 0..15 : p = t>>2, q = t&3
  const int j2 = blockIdx.y;  // 0..62
  const int m1 = 2 * j2 + 1, m2 = 2 * j2 + 2;
  const u16* TA = T + ((size_t)m1 * 4 + (t >> 2)) * 16384;  // odd -> row-major
  const u16* TB = T + ((size_t)m2 * 4 + (t & 3)) * 16384;   // even -> [n][k] flat
  loadM(Ald, TA);
  loadM(Bld, TB);
  __syncthreads();
  AccW acc;
  mfma_w16(Ald, Bld, acc);
  __syncthreads();
  bounce_store(Ald, acc, 1.f, (j2 % 2) == 0);
  __syncthreads();
  copy_out(Ald, TT + ((size_t)j2 * 16 + t) * 16384);
}

// ---------------- k1c: Gram partials G[j2][kc] = V V^T over K-chunk ----------
__global__ __launch_bounds__(256) void k1c(const u16* __restrict__ TT,
                                           float* __restrict__ Gpart) {
  __shared__ float Gp[1024];
  const int j2 = blockIdx.x, kc = blockIdx.y;
  const int tid = threadIdx.x;
  const int w = tid >> 6, lane = tid & 63;
  const int l16 = lane & 15, quad = lane >> 4;
  const u16* V = TT + (size_t)j2 * 16 * 16384 + (size_t)l16 * 16384;
  const int k0 = kc * 4096 + w * 1024;
  f32x4 acc = (f32x4){0.f, 0.f, 0.f, 0.f};
  for (int kk = k0; kk < k0 + 1024; kk += 32) {
    short8 av = *(const short8*)(V + kk + quad * 8);
    acc = __builtin_amdgcn_mfma_f32_16x16x32_bf16(av, av, acc, 0, 0, 0);
  }
#pragma unroll
  for (int i = 0; i < 4; i++)
    Gp[w * 256 + (quad * 4 + i) * 16 + l16] = acc[i];
  __syncthreads();
  Gpart[((size_t)j2 * 4 + kc) * 256 + tid] =
      Gp[tid] + Gp[256 + tid] + Gp[512 + tid] + Gp[768 + tid];
}

// ---------------- k2ns: coeffs/norms/logs (bx<63) + special chain (bx>=63) ----
__global__ __launch_bounds__(128) void k2ns(const float* __restrict__ x,
                                            const float* __restrict__ Gpart,
                                            const float* __restrict__ core0,
                                            const float* __restrict__ cores,
                                            const u16* __restrict__ T,
                                            float* __restrict__ cbuf,
                                            float* __restrict__ sA,
                                            float* __restrict__ logs) {
  __shared__ float Gs[256];
  __shared__ float svec[128];
  __shared__ float red[8];
  const int bx = blockIdx.x, tid = threadIdx.x;
  if (bx < 63) {
    const int j2 = bx;
#pragma unroll
    for (int i = 0; i < 2; i++) {
      int t2 = tid + i * 128;
      float s = 0.f;
#pragma unroll
      for (int kc = 0; kc < 4; kc++)
        s += Gpart[((size_t)j2 * 4 + kc) * 256 + t2];
      Gs[t2] = s;
    }
    __syncthreads();
    if (tid < 64) {
      const int b = tid;
      const float* xb = x + b * 256;
      const int m1 = 2 * j2 + 1, m2 = 2 * j2 + 2;
      float a1 = xb[2 * m1 + 2], b1 = xb[2 * m1 + 3];
      float a2 = xb[2 * m2 + 2], b2 = xb[2 * m2 + 3];
      float c1[4] = {1.f, b1, a1, a1 * b1};
      float c2[4] = {1.f, b2, a2, a2 * b2};
      float c[16];
#pragma unroll
      for (int p = 0; p < 4; p++)
#pragma unroll
        for (int q = 0; q < 4; q++) c[p * 4 + q] = c1[p] * c2[q];
      float n2 = 0.f;
#pragma unroll
      for (int t = 0; t < 16; t++) {
        float s = 0.f;
#pragma unroll
        for (int u = 0; u < 16; u++) s += Gs[t * 16 + u] * c[u];
        n2 += c[t] * s;
      }
      float n = fmaxf(sqrtf(n2), 1e-12f);
      logs[b * 127 + 1 + j2] = logf(n);
      float inv = 1.f / n;
#pragma unroll
      for (int t = 0; t < 16; t++)
        cbuf[((size_t)j2 * 64 + b) * 16 + t] = c[t] * inv;  // prescaled by 1/n
    }
  } else {
    const int b = bx - 63;
    const float* xb = x + b * 256;
    float x0 = xb[0], x1 = xb[1];
    svec[tid] = core0[tid] * (1.f - x0) + core0[128 + tid] * x0;
    __syncthreads();
    float acc1 = 0.f;
    for (int k = 0; k < 128; k++) {
      float m0 = cores[(k * 2 + 0) * 128 + tid];
      float m1 = cores[(k * 2 + 1) * 128 + tid];
      acc1 += svec[k] * (m0 + x1 * (m1 - m0));
    }
    float tot = block_sum(acc1 * acc1, red, 2);
    float n1 = fmaxf(sqrtf(tot), 1e-12f);
    float ln = logf(n1);
    svec[tid] = acc1 / n1;
    __syncthreads();
    float a = xb[2], bb = xb[3], ab = a * bb;
    float acc2 = 0.f;
    for (int k8 = 0; k8 < 16; k8++) {
      union { uint4 v; u16 s[8]; } q00, q01, q10, q11;
      q00.v = *(const uint4*)(T + tid * 128 + k8 * 8);
      q01.v = *(const uint4*)(T + 16384 + tid * 128 + k8 * 8);
      q10.v = *(const uint4*)(T + 32768 + tid * 128 + k8 * 8);
      q11.v = *(const uint4*)(T + 49152 + tid * 128 + k8 * 8);
#pragma unroll
      for (int e = 0; e < 8; e++) {
        float pk = b2f(q00.s[e]) + a * b2f(q10.s[e]) + bb * b2f(q01.s[e]) +
                   ab * b2f(q11.s[e]);
        acc2 += svec[k8 * 8 + e] * pk;
      }
    }
    float tot2 = block_sum(acc2 * acc2, red, 2);
    float n2 = fmaxf(sqrtf(tot2), 1e-12f);
    sA[b * 128 + tid] = acc2 / n2;
    if (tid == 0) logs[b * 127 + 0] = ln + logf(n2);
  }
}

// ---------------- k2c: combine; coefficients via scalar (SGPR) loads ---------
// grid (32,63): each TT element read by exactly one block (no replication).
// (256,4): 128-VGPR cap, v[16][2] fits (VGPR 40 measured). Block-uniform
// coefficients -> uniform-address float4 loads lower to s_load_dwordx4.
__global__ __launch_bounds__(256, 4) void k2c(const u16* __restrict__ TT,
                                              const float* __restrict__ cbuf,
                                              u16* __restrict__ M0) {
  const int slice = blockIdx.x;  // 0..31, 512 elems each
  const int j2 = blockIdx.y;
  const int tid = threadIdx.x;
  const int e0 = slice * 512 + tid * 2;
  float v[16][2];
#pragma unroll
  for (int t = 0; t < 16; t++) {
    union { uint32_t u; u16 s[2]; } q;
    q.u = *(const uint32_t*)(TT + ((size_t)j2 * 16 + t) * 16384 + e0);
    v[t][0] = b2f(q.s[0]);
    v[t][1] = b2f(q.s[1]);
  }
  const float4* cb4 = (const float4*)(cbuf + (size_t)j2 * 1024);  // uniform base
  u16* out = M0 + (size_t)j2 * 16384 + e0;
#pragma unroll 4
  for (int b = 0; b < 64; b++) {
    float4 c0 = cb4[b * 4 + 0];
    float4 c1 = cb4[b * 4 + 1];
    float4 c2 = cb4[b * 4 + 2];
    float4 c3 = cb4[b * 4 + 3];
    float cc[16] = {c0.x, c0.y, c0.z, c0.w, c1.x, c1.y, c1.z, c1.w,
                    c2.x, c2.y, c2.z, c2.w, c3.x, c3.y, c3.z, c3.w};
    float o0 = 0.f, o1 = 0.f;
#pragma unroll
    for (int t = 0; t < 16; t++) {
      o0 += cc[t] * v[t][0];
      o1 += cc[t] * v[t][1];
    }
    union { uint32_t u; u16 s[2]; } r;
    r.s[0] = f2b(o0);
    r.s[1] = f2b(o1);
    *(uint32_t*)(out + (size_t)b * 63 * 16384) = r.u;
  }
}

// ---------------- round2x: TWO rounds fused, 2-buffer, folded logs -----------
// grid (1 + count_out, 64).  p>=1 (m=p-1):
//   stage In[4m+3],In[4m+4] -> a1 = mm; restage In[4m+5],In[4m+6] -> a2 = mm
//   (a1 lives in VGPRs across the restage — active MFMA operand pattern, not
//   a parked aggregate); bounce a1->L0 (row-major), a2->L1 (transposed);
//   a3 = L0@L1; n3 = ||a3|| is the ONLY reduction (folded logs); mid log
//   slots <- 0. bounce a3/n3 -> L0 (parity); copy_out.
// p==0: special chain, same folding.
__global__ __launch_bounds__(1024, 4) void round2x(const u16* __restrict__ In,
                                                   u16* __restrict__ Out,
                                                   const float* __restrict__ sIn,
                                                   float* __restrict__ sOut,
                                                   float* __restrict__ logs,
                                                   int count_in, int count_out,
                                                   int slot0, int slot1) {
  __shared__ u16 L0[128 * HP], L1[128 * HP];
  __shared__ float svf[256];
  __shared__ float red[16];
  const int b = blockIdx.y, p = blockIdx.x, tid = threadIdx.x;
  const u16* base = In + (size_t)b * count_in * 16384;
  if (p == 0) {
    if (tid < 128) svf[tid] = sIn[b * 128 + tid];
    loadM(L0, base + 1 * 16384);   // In[1]: odd -> row-major -> A
    loadM(L1, base + 2 * 16384);   // In[2]: even -> transposed -> B
    __syncthreads();
    // acc0 = svec @ In[0] (unnormalized); In[0] stored transposed [h][l]
    float acc0 = 0.f;
    if (tid < 128) {
      for (int k8 = 0; k8 < 16; k8++) {
        union { uint4 v; u16 s[8]; } q;
        q.v = *(const uint4*)(base + tid * 128 + k8 * 8);
#pragma unroll
        for (int e = 0; e < 8; e++) acc0 += svf[k8 * 8 + e] * b2f(q.s[e]);
      }
    }
    AccW accq;
    mfma_w16(L0, L1, accq);        // Q = In[1]@In[2], unnormalized
    __syncthreads();               // all reads of L0/L1 done
    bounce_store(L0, accq, 1.f, true);  // Qt[c][r]
    if (tid < 128) svf[128 + tid] = acc0;
    if (tid == 0) {
      logs[b * 127 + slot0] = 0.f;
      logs[b * 127 + slot0 + 1] = 0.f;
    }
    __syncthreads();
    // svec'' = normalize((svec@In0) @ Q); single log absorbs all three norms
    float acc2 = 0.f;
    if (tid < 128) {
      for (int l = 0; l < 128; l++) acc2 += svf[128 + l] * b2f(L0[tid * HP + l]);
    }
    float t2 = bsum16((tid < 128) ? acc2 * acc2 : 0.f, red);
    float n2 = fmaxf(sqrtf(t2), 1e-12f);
    if (tid == 0) logs[b * 127 + slot1] = logf(n2);
    if (tid < 128) sOut[b * 128 + tid] = acc2 / n2;
  } else {
    const int m = p - 1;
    loadM(L0, base + (size_t)(4 * m + 3) * 16384);
    loadM(L1, base + (size_t)(4 * m + 4) * 16384);
    __syncthreads();
    AccW a1;
    mfma_w16(L0, L1, a1);
    __syncthreads();               // all reads done -> restage
    loadM(L0, base + (size_t)(4 * m + 5) * 16384);
    loadM(L1, base + (size_t)(4 * m + 6) * 16384);
    __syncthreads();
    AccW a2;
    mfma_w16(L0, L1, a2);
    __syncthreads();               // all reads done -> bounce over operands
    bounce_store(L0, a1, 1.f, false);  // mid 2m+1 (odd) -> A row-major
    bounce_store(L1, a2, 1.f, true);   // mid 2m+2 (even) -> B transposed
    if (tid == 0) {                    // folded logs: zero the mid slots
      logs[b * 127 + slot0 + 2 + 2 * m] = 0.f;
      logs[b * 127 + slot0 + 3 + 2 * m] = 0.f;
    }
    __syncthreads();
    AccW a3;
    mfma_w16(L0, L1, a3);
    float t3 = bsum16(acc_sumsq(a3), red);  // its barrier also fences L0 reads
    float n3 = fmaxf(sqrtf(t3), 1e-12f);
    if (tid == 0) logs[b * 127 + slot1 + 1 + m] = logf(n3);
    bounce_store(L0, a3, 1.f / n3, (m % 2) == 0);
    __syncthreads();
    copy_out(L0, Out + ((size_t)b * count_out + m) * 16384);
  }
}

// ---------------- r7f: R7 + R8 + logits; folded logs -> 1 reduction ----------
__global__ __launch_bounds__(1024, 8) void r7f(const u16* __restrict__ In,
                                               const float* __restrict__ sIn,
                                               const float* __restrict__ logs,
                                               const float* __restrict__ cls,
                                               float* __restrict__ out) {
  __shared__ u16 Ald[128 * HP], Bld[128 * HP];
  __shared__ float svec[128], ovec[128], red[16];
  const int b = blockIdx.x, tid = threadIdx.x;
  if (tid < 128) svec[tid] = sIn[b * 128 + tid];
  loadM(Ald, In + ((size_t)b * 3 + 1) * 16384);   // row-major
  loadM(Bld, In + ((size_t)b * 3 + 2) * 16384);   // transposed
  __syncthreads();
  AccW acc;
  mfma_w16(Ald, Bld, acc);   // C = In1@In2, unnormalized
  // acc0 = svec @ In0 (unnormalized); In0 transposed layout
  const u16* M0p = In + (size_t)b * 3 * 16384;
  float acc0 = 0.f;
  if (tid < 128) {
    for (int k8 = 0; k8 < 16; k8++) {
      union { uint4 v; u16 s[8]; } q;
      q.v = *(const uint4*)(M0p + tid * 128 + k8 * 8);
#pragma unroll
      for (int e = 0; e < 8; e++) acc0 += svec[k8 * 8 + e] * b2f(q.s[e]);
    }
  }
  __syncthreads();  // all Ald/Bld reads done
  bounce_store(Ald, acc, 1.f, true);  // C^T [c][r]
  if (tid < 128) ovec[tid] = acc0;
  __syncthreads();
  // res = (svec@In0) @ C; single log absorbs n0, n1, n2
  float acc2 = 0.f;
  if (tid < 128) {
    for (int r = 0; r < 128; r++) acc2 += ovec[r] * b2f(Ald[tid * HP + r]);
  }
  float tot = bsum16((tid < 128) ? acc2 * acc2 : 0.f, red);
  float n = fmaxf(sqrtf(tot), 1e-12f);
  float lg = logf(n);
  if (tid < 128) svec[tid] = acc2 / n;
  __syncthreads();
  if (tid < 10) {
    float a = 0.f;
    for (int h = 0; h < 128; h++) a += svec[h] * cls[tid * 128 + h];
    float L = lg;
    for (int i = 0; i < 124; i++) L += logs[b * 127 + i];
    out[b * 10 + tid] = a + L;
  }
}

extern "C" void kernel_launch(void* const* d_in, const int* in_sizes, int n_in,
                              void* d_out, int out_size, void* d_ws, size_t ws_size,
                              hipStream_t stream) {
  (void)in_sizes; (void)n_in; (void)out_size; (void)ws_size;
  const float* x     = (const float*)d_in[0];  // (64,256)
  const float* core0 = (const float*)d_in[1];  // (1,2,128)
  const float* cores = (const float*)d_in[2];  // (255,128,2,128)
  const float* cls   = (const float*)d_in[3];  // (10,128)
  float* out = (float*)d_out;
  char* ws = (char*)d_ws;

  // Region A (65 MB): early = T (16.6 MB) + TT (33 MB); later reused as M2.
  constexpr size_t SZ_T  = (size_t)127 * 4 * 16384 * 2;   //  16,646,144
  constexpr size_t SZ_A  = (size_t)64 * 31 * 16384 * 2;   //  65,011,712
  constexpr size_t SZ_M0 = (size_t)64 * 63 * 16384 * 2;   // 132,120,576

  u16*   T    = (u16*)(ws);
  u16*   TT   = (u16*)(ws + SZ_T);
  u16*   M2   = (u16*)(ws);            // aliases T+TT after k2c completes
  u16*   M0   = (u16*)(ws + SZ_A);
  char*  tail0 = ws + SZ_A + SZ_M0;
  float* Gpart = (float*)(tail0);                      // 63*4*256*4 = 258,048
  float* cbuf = (float*)(tail0 + 262144);              // 63*64*16*4 = 258,048
  float* sA   = (float*)(tail0 + 262144 + 262144);
  float* sB   = (float*)(tail0 + 262144 + 262144 + 32768);
  float* logs = (float*)(tail0 + 262144 + 262144 + 65536);

  k1  <<<dim3(127, 2), 1024, 0, stream>>>(cores, T);
  k1b <<<dim3(16, 63), 1024, 0, stream>>>(T, TT);
  k1c <<<dim3(63, 4), 256, 0, stream>>>(TT, Gpart);
  k2ns<<<dim3(127), 128, 0, stream>>>(x, Gpart, core0, cores, T, cbuf, sA, logs);
  k2c <<<dim3(32, 63), 256, 0, stream>>>(TT, cbuf, M0);
  // log slots: 0 special(r1+r2), 1..63 pairs(r1+r2);
  //   R3R4: 64,65 <- 0, 66..95 <- 0 (mids), 96 sp-total, 97..111 out pairs;
  //   R5R6: 112,113 <- 0, 114..119 <- 0, 120 sp-total, 121..123 out;
  //   r7f folds its three logs into one local value.
  round2x<<<dim3(16, 64), 1024, 0, stream>>>(M0, M2, sA, sB, logs, 63, 15, 64, 96);
  round2x<<<dim3(4, 64), 1024, 0, stream>>>(M2, M0, sB, sA, logs, 15, 3, 112, 120);
  r7f  <<<dim3(64), 1024, 0, stream>>>(M0, sA, logs, cls, out);
}

// Round 9
// 227.643 us; speedup vs baseline: 2.0402x; 1.0636x over previous
//
#include <hip/hip_runtime.h>
#include <stdint.h>

// MPS classifier forward, MI355X.
//   k1  : (127,2) blocks, 2 round-1 basis products per block (A-row split)
//   k1b : (16,63) blocks, round-2 basis TT_t = T1_p @ T2_q (LDS-staged; r4:
//         never feed MFMA from scattered global — 84.6 vs 49.4 us)
//   k1c : (63,4) blocks, Gram partials over K-chunks
//   k2ns: 127 blocks: bx<63 -> coeffs/norms/logs; bx>=63 -> special chain r1+r2
//   k2c : (32,63) combine M0 = sum_t c'_t TT_t; 2 elems/thread (r0-proven).
//         RULES: (1) every TT element read by EXACTLY ONE block; (2) VGPR cap
//         512/minw; (3) block-uniform coeffs via SGPRs.
//         HARD RULE (r2+r6): any multi-uint4 per-thread aggregate held live
//         across __syncthreads()/MFMA in a 16-wave block SPILLS.
//   tree: R3..R6 in ONE single-pass kernel, grid (4,64) = 1 block/CU.
//         PRECISION RULE (r8): fold <= 2 levels (3 norms) per normalization —
//         the full 15-norm fold FAILED absmax 18 vs 10.08 (4 levels of
//         unnormalized bf16 intermediates compound independent rounding vs
//         the reference's normalized grid). So: each M2 subtree normalizes
//         (r5-proven R3R4 fold, log->97+midx), upper stage is the r5-proven
//         R5R6 fold (log->121+m). Special = two chained r5-special folds
//         (logs 96, 120). Numerics == the passing r7 config, fused.
//         M2 never touches HBM; 15 matmuls/block hide cold staging.
//   r7f : R7 + R8 + logits fused, folded logs, 1 reduction.

typedef unsigned short u16;
typedef __attribute__((ext_vector_type(8))) short short8;
typedef __attribute__((ext_vector_type(4))) float f32x4;

#define HP 136  // LDS row stride in bf16: 272 B, 16B-aligned, 2-way-bank-free

__device__ __forceinline__ u16 f2b(float f) {
  uint32_t u = __builtin_bit_cast(uint32_t, f);
  u += 0x7FFFu + ((u >> 16) & 1u);
  return (u16)(u >> 16);
}
__device__ __forceinline__ float b2f(u16 b) {
  uint32_t u = ((uint32_t)b) << 16;
  return __builtin_bit_cast(float, u);
}

struct AccW { f32x4 t[2][2]; };  // 16-wave config: 32x32 wave tile

// 1024-thread (16-wave) 128x128x128 from LDS. A: [m][k], B: [n][k], stride HP.
__device__ __forceinline__ void mfma_w16(const u16* Alds, const u16* Blds,
                                         AccW& acc) {
  const int tid = threadIdx.x;
  const int wid = tid >> 6, lane = tid & 63;
  const int wm = (wid >> 2) * 32, wn = (wid & 3) * 32;
  const int l16 = lane & 15, quad = lane >> 4;
#pragma unroll
  for (int tm = 0; tm < 2; tm++)
#pragma unroll
    for (int tn = 0; tn < 2; tn++)
      acc.t[tm][tn] = (f32x4){0.f, 0.f, 0.f, 0.f};
#pragma unroll
  for (int kk = 0; kk < 128; kk += 32) {
    short8 af[2], bf[2];
#pragma unroll
    for (int t = 0; t < 2; t++) {
      af[t] = *(const short8*)(Alds + (wm + t * 16 + l16) * HP + kk + quad * 8);
      bf[t] = *(const short8*)(Blds + (wn + t * 16 + l16) * HP + kk + quad * 8);
    }
#pragma unroll
    for (int tm = 0; tm < 2; tm++)
#pragma unroll
      for (int tn = 0; tn < 2; tn++)
        acc.t[tm][tn] = __builtin_amdgcn_mfma_f32_16x16x32_bf16(
            af[tm], bf[tn], acc.t[tm][tn], 0, 0, 0);
  }
}

__device__ __forceinline__ float acc_sumsq(const AccW& acc) {
  float ss = 0.f;
#pragma unroll
  for (int tm = 0; tm < 2; tm++)
#pragma unroll
    for (int tn = 0; tn < 2; tn++)
#pragma unroll
      for (int i = 0; i < 4; i++) {
        float v = acc.t[tm][tn][i];
        ss += v * v;
      }
  return ss;
}

// Write acc into bounce LDS (stride HP). transposed -> buffer row = col index.
// C/D layout (m89): row = quad*4 + reg, col = lane&15 per 16x16 tile.
__device__ __forceinline__ void bounce_store(u16* Lb, const AccW& acc, float scale,
                                             bool transposed) {
  const int tid = threadIdx.x;
  const int wid = tid >> 6, lane = tid & 63;
  const int wm = (wid >> 2) * 32, wn = (wid & 3) * 32;
  const int l16 = lane & 15, quad = lane >> 4;
#pragma unroll
  for (int tm = 0; tm < 2; tm++)
#pragma unroll
    for (int tn = 0; tn < 2; tn++)
#pragma unroll
      for (int i = 0; i < 4; i++) {
        int r = wm + tm * 16 + quad * 4 + i;
        int c = wn + tn * 16 + l16;
        int key = transposed ? c : r, sec = transposed ? r : c;
        Lb[key * HP + sec] = f2b(acc.t[tm][tn][i] * scale);
      }
}

// 1024 threads: copy bounce LDS -> global, fully coalesced uint4.
__device__ __forceinline__ void copy_out(const u16* Lb, u16* out) {
  const int tid = threadIdx.x;
#pragma unroll
  for (int i = 0; i < 2; i++) {
    int g8 = tid + i * 1024;  // 0..2047 uint4 units
    int row = g8 >> 4, c8 = g8 & 15;
    *(uint4*)(out + g8 * 8) = *(const uint4*)(Lb + row * HP + c8 * 8);
  }
}

// 1024 threads: global matrix (32 KB) -> LDS (stride HP), coalesced uint4.
__device__ __forceinline__ void loadM(u16* Lb, const u16* __restrict__ src) {
  const int tid = threadIdx.x;
#pragma unroll
  for (int i = 0; i < 2; i++) {
    int g8 = tid + i * 1024;
    int r = g8 >> 4, c8 = g8 & 15;
    *(uint4*)(Lb + r * HP + c8 * 8) = *(const uint4*)(src + g8 * 8);
  }
}

// legacy 3-barrier block reduction (k2ns, 2 waves)
__device__ __forceinline__ float block_sum(float v, float* red, int nw) {
#pragma unroll
  for (int off = 32; off > 0; off >>= 1) v += __shfl_down(v, off);
  int wid = threadIdx.x >> 6;
  if ((threadIdx.x & 63) == 0) red[wid] = v;
  __syncthreads();
  if (threadIdx.x == 0) {
    float s = 0.f;
    for (int w = 0; w < nw; w++) s += red[w];
    red[0] = s;
  }
  __syncthreads();
  float s = red[0];
  __syncthreads();
  return s;
}

// lean 1-barrier 16-wave reduction; WAR-safe here: >=2 barriers always sit
// between successive red uses (subtree staging barriers).
__device__ __forceinline__ float bsum16(float v, float* red) {
#pragma unroll
  for (int off = 32; off > 0; off >>= 1) v += __shfl_down(v, off);
  if ((threadIdx.x & 63) == 0) red[threadIdx.x >> 6] = v;
  __syncthreads();
  float s = 0.f;
#pragma unroll
  for (int w = 0; w < 16; w++) s += red[w];
  return s;
}

// ---------------- k1: two round-1 basis products per block (A-row split) -----
__global__ __launch_bounds__(1024) void k1(const float* __restrict__ cores,
                                           u16* __restrict__ T) {
  __shared__ u16 Ald[128 * HP], B0[128 * HP], B1[128 * HP];
  const int j = blockIdx.x;   // 0..126 -> cores (2j+1, 2j+2)
  const int p = blockIdx.y;   // 0: A0 row (coeffs 1,b), 1: A1 row (coeffs a,ab)
  const float* c1 = cores + (size_t)(2 * j + 1) * 32768;
  const float* c2 = cores + (size_t)(2 * j + 2) * 32768;
  const int tid = threadIdx.x;
#pragma unroll 4
  for (int i = 0; i < 16; i++) {
    int lh = tid + i * 1024;
    int l = lh >> 7, h = lh & 127;
    float a0 = c1[(l * 2 + 0) * 128 + h];
    float av = p ? (c1[(l * 2 + 1) * 128 + h] - a0) : a0;
    Ald[l * HP + h] = f2b(av);
    float b0 = c2[(l * 2 + 0) * 128 + h];
    float b1 = c2[(l * 2 + 1) * 128 + h];
    B0[h * HP + l] = f2b(b0);  // B basis transposed in LDS
    B1[h * HP + l] = f2b(b1 - b0);
  }
  __syncthreads();
  const bool tr = (j % 2) == 0;  // even -> consumed as B operand -> store C^T
  u16* Tj = T + ((size_t)j * 4 + p * 2) * 16384;
  AccW q0, q1;
  mfma_w16(Ald, B0, q0);
  mfma_w16(Ald, B1, q1);
  __syncthreads();  // A dead -> bounce
  bounce_store(Ald, q0, 1.f, tr); __syncthreads();
  copy_out(Ald, Tj + 0 * 16384);  __syncthreads();
  bounce_store(Ald, q1, 1.f, tr); __syncthreads();
  copy_out(Ald, Tj + 1 * 16384);
}

// ---------------- k1b: round-2 basis TT_t = T1_p @ T2_q (staged, proven) -----
__global__ __launch_bounds__(1024, 8) void k1b(const u16* __restrict__ T,
                                               u16* __restrict__ TT) {
  __shared__ u16 Ald[128 * HP], Bld[128 * HP];
  const int t = blockIdx.x;   // 0..15 : p = t>>2, q = t&3
  const int j2 = blockIdx.y;  // 0..62
  const int m1 = 2 * j2 + 1, m2 = 2 * j2 + 2;
  const u16* TA = T + ((size_t)m1 * 4 + (t >> 2)) * 16384;  // odd -> row-major
  const u16* TB = T + ((size_t)m2 * 4 + (t & 3)) * 16384;   // even -> [n][k] flat
  loadM(Ald, TA);
  loadM(Bld, TB);
  __syncthreads();
  AccW acc;
  mfma_w16(Ald, Bld, acc);
  __syncthreads();
  bounce_store(Ald, acc, 1.f, (j2 % 2) == 0);
  __syncthreads();
  copy_out(Ald, TT + ((size_t)j2 * 16 + t) * 16384);
}

// ---------------- k1c: Gram partials G[j2][kc] = V V^T over K-chunk ----------
__global__ __launch_bounds__(256) void k1c(const u16* __restrict__ TT,
                                           float* __restrict__ Gpart) {
  __shared__ float Gp[1024];
  const int j2 = blockIdx.x, kc = blockIdx.y;
  const int tid = threadIdx.x;
  const int w = tid >> 6, lane = tid & 63;
  const int l16 = lane & 15, quad = lane >> 4;
  const u16* V = TT + (size_t)j2 * 16 * 16384 + (size_t)l16 * 16384;
  const int k0 = kc * 4096 + w * 1024;
  f32x4 acc = (f32x4){0.f, 0.f, 0.f, 0.f};
  for (int kk = k0; kk < k0 + 1024; kk += 32) {
    short8 av = *(const short8*)(V + kk + quad * 8);
    acc = __builtin_amdgcn_mfma_f32_16x16x32_bf16(av, av, acc, 0, 0, 0);
  }
#pragma unroll
  for (int i = 0; i < 4; i++)
    Gp[w * 256 + (quad * 4 + i) * 16 + l16] = acc[i];
  __syncthreads();
  Gpart[((size_t)j2 * 4 + kc) * 256 + tid] =
      Gp[tid] + Gp[256 + tid] + Gp[512 + tid] + Gp[768 + tid];
}

// ---------------- k2ns: coeffs/norms/logs (bx<63) + special chain (bx>=63) ----
__global__ __launch_bounds__(128) void k2ns(const float* __restrict__ x,
                                            const float* __restrict__ Gpart,
                                            const float* __restrict__ core0,
                                            const float* __restrict__ cores,
                                            const u16* __restrict__ T,
                                            float* __restrict__ cbuf,
                                            float* __restrict__ sA,
                                            float* __restrict__ logs) {
  __shared__ float Gs[256];
  __shared__ float svec[128];
  __shared__ float red[8];
  const int bx = blockIdx.x, tid = threadIdx.x;
  if (bx < 63) {
    const int j2 = bx;
#pragma unroll
    for (int i = 0; i < 2; i++) {
      int t2 = tid + i * 128;
      float s = 0.f;
#pragma unroll
      for (int kc = 0; kc < 4; kc++)
        s += Gpart[((size_t)j2 * 4 + kc) * 256 + t2];
      Gs[t2] = s;
    }
    __syncthreads();
    if (tid < 64) {
      const int b = tid;
      const float* xb = x + b * 256;
      const int m1 = 2 * j2 + 1, m2 = 2 * j2 + 2;
      float a1 = xb[2 * m1 + 2], b1 = xb[2 * m1 + 3];
      float a2 = xb[2 * m2 + 2], b2 = xb[2 * m2 + 3];
      float c1[4] = {1.f, b1, a1, a1 * b1};
      float c2[4] = {1.f, b2, a2, a2 * b2};
      float c[16];
#pragma unroll
      for (int p = 0; p < 4; p++)
#pragma unroll
        for (int q = 0; q < 4; q++) c[p * 4 + q] = c1[p] * c2[q];
      float n2 = 0.f;
#pragma unroll
      for (int t = 0; t < 16; t++) {
        float s = 0.f;
#pragma unroll
        for (int u = 0; u < 16; u++) s += Gs[t * 16 + u] * c[u];
        n2 += c[t] * s;
      }
      float n = fmaxf(sqrtf(n2), 1e-12f);
      logs[b * 127 + 1 + j2] = logf(n);
      float inv = 1.f / n;
#pragma unroll
      for (int t = 0; t < 16; t++)
        cbuf[((size_t)j2 * 64 + b) * 16 + t] = c[t] * inv;  // prescaled by 1/n
    }
  } else {
    const int b = bx - 63;
    const float* xb = x + b * 256;
    float x0 = xb[0], x1 = xb[1];
    svec[tid] = core0[tid] * (1.f - x0) + core0[128 + tid] * x0;
    __syncthreads();
    float acc1 = 0.f;
    for (int k = 0; k < 128; k++) {
      float m0 = cores[(k * 2 + 0) * 128 + tid];
      float m1 = cores[(k * 2 + 1) * 128 + tid];
      acc1 += svec[k] * (m0 + x1 * (m1 - m0));
    }
    float tot = block_sum(acc1 * acc1, red, 2);
    float n1 = fmaxf(sqrtf(tot), 1e-12f);
    float ln = logf(n1);
    svec[tid] = acc1 / n1;
    __syncthreads();
    float a = xb[2], bb = xb[3], ab = a * bb;
    float acc2 = 0.f;
    for (int k8 = 0; k8 < 16; k8++) {
      union { uint4 v; u16 s[8]; } q00, q01, q10, q11;
      q00.v = *(const uint4*)(T + tid * 128 + k8 * 8);
      q01.v = *(const uint4*)(T + 16384 + tid * 128 + k8 * 8);
      q10.v = *(const uint4*)(T + 32768 + tid * 128 + k8 * 8);
      q11.v = *(const uint4*)(T + 49152 + tid * 128 + k8 * 8);
#pragma unroll
      for (int e = 0; e < 8; e++) {
        float pk = b2f(q00.s[e]) + a * b2f(q10.s[e]) + bb * b2f(q01.s[e]) +
                   ab * b2f(q11.s[e]);
        acc2 += svec[k8 * 8 + e] * pk;
      }
    }
    float tot2 = block_sum(acc2 * acc2, red, 2);
    float n2 = fmaxf(sqrtf(tot2), 1e-12f);
    sA[b * 128 + tid] = acc2 / n2;
    if (tid == 0) logs[b * 127 + 0] = ln + logf(n2);
  }
}

// ---------------- k2c: combine; coefficients via scalar (SGPR) loads ---------
__global__ __launch_bounds__(256, 4) void k2c(const u16* __restrict__ TT,
                                              const float* __restrict__ cbuf,
                                              u16* __restrict__ M0) {
  const int slice = blockIdx.x;  // 0..31, 512 elems each
  const int j2 = blockIdx.y;
  const int tid = threadIdx.x;
  const int e0 = slice * 512 + tid * 2;
  float v[16][2];
#pragma unroll
  for (int t = 0; t < 16; t++) {
    union { uint32_t u; u16 s[2]; } q;
    q.u = *(const uint32_t*)(TT + ((size_t)j2 * 16 + t) * 16384 + e0);
    v[t][0] = b2f(q.s[0]);
    v[t][1] = b2f(q.s[1]);
  }
  const float4* cb4 = (const float4*)(cbuf + (size_t)j2 * 1024);  // uniform base
  u16* out = M0 + (size_t)j2 * 16384 + e0;
#pragma unroll 4
  for (int b = 0; b < 64; b++) {
    float4 c0 = cb4[b * 4 + 0];
    float4 c1 = cb4[b * 4 + 1];
    float4 c2 = cb4[b * 4 + 2];
    float4 c3 = cb4[b * 4 + 3];
    float cc[16] = {c0.x, c0.y, c0.z, c0.w, c1.x, c1.y, c1.z, c1.w,
                    c2.x, c2.y, c2.z, c2.w, c3.x, c3.y, c3.z, c3.w};
    float o0 = 0.f, o1 = 0.f;
#pragma unroll
    for (int t = 0; t < 16; t++) {
      o0 += cc[t] * v[t][0];
      o1 += cc[t] * v[t][1];
    }
    union { uint32_t u; u16 s[2]; } r;
    r.s[0] = f2b(o0);
    r.s[1] = f2b(o1);
    *(uint32_t*)(out + (size_t)b * 63 * 16384) = r.u;
  }
}

// ---------------- tree: R3..R6 fused, single pass, M2-level normalization ----
// subtree3n: NORMALIZED M2[midx] from 4 M0 leaves (r5-proven R3R4 fold:
// mids unnormalized, one reduction; log -> 97+midx, mid slots zeroed).
// Ends at bsum16's barrier: caller may immediately reuse L0/L1.
__device__ __forceinline__ AccW subtree3n(const u16* __restrict__ base, int midx,
                                          u16* L0, u16* L1, float* red,
                                          float* logs, int b, float& nOut) {
  loadM(L0, base + (size_t)(4 * midx + 3) * 16384);
  loadM(L1, base + (size_t)(4 * midx + 4) * 16384);
  __syncthreads();
  AccW a1;
  mfma_w16(L0, L1, a1);
  __syncthreads();
  loadM(L0, base + (size_t)(4 * midx + 5) * 16384);
  loadM(L1, base + (size_t)(4 * midx + 6) * 16384);
  __syncthreads();
  AccW a2;
  mfma_w16(L0, L1, a2);
  __syncthreads();
  bounce_store(L0, a1, 1.f, false);  // mid odd -> A row-major (unnormalized)
  bounce_store(L1, a2, 1.f, true);   // mid even -> B transposed
  if (threadIdx.x == 0) {
    logs[b * 127 + 66 + 2 * midx] = 0.f;
    logs[b * 127 + 67 + 2 * midx] = 0.f;
  }
  __syncthreads();
  AccW a3;
  mfma_w16(L0, L1, a3);
  float t = bsum16(acc_sumsq(a3), red);  // barrier fences L0/L1 reads
  float n = fmaxf(sqrtf(t), 1e-12f);
  if (threadIdx.x == 0) logs[b * 127 + 97 + midx] = logf(n);
  nOut = n;
  return a3;
}

__global__ __launch_bounds__(1024, 4) void tree(const u16* __restrict__ In,
                                                u16* __restrict__ Out,
                                                const float* __restrict__ sIn,
                                                float* __restrict__ sOut,
                                                float* __restrict__ logs) {
  __shared__ u16 L0[128 * HP], L1[128 * HP], L2[128 * HP], L3[128 * HP];
  __shared__ float svf[256];
  __shared__ float red[16];
  const int b = blockIdx.y, p = blockIdx.x, tid = threadIdx.x;
  const u16* base = In + (size_t)b * 63 * 16384;
  if (p < 3) {
    const int m = p;
    float n1, n2, n3, n4;
    AccW t1 = subtree3n(base, 4 * m + 3, L0, L1, red, logs, b, n1);
    bounce_store(L2, t1, 1.f / n1, false);   // M2n -> L2 row (A)
    AccW t2 = subtree3n(base, 4 * m + 4, L0, L1, red, logs, b, n2);
    bounce_store(L3, t2, 1.f / n2, true);    // M2n -> L3 tr (B)
    __syncthreads();
    AccW pa;
    mfma_w16(L2, L3, pa);                    // P1 = M2n@M2n (unnormalized)
    __syncthreads();
    bounce_store(L2, pa, 1.f, false);        // P1 -> L2 row
    AccW t3 = subtree3n(base, 4 * m + 5, L0, L1, red, logs, b, n3);
    bounce_store(L3, t3, 1.f / n3, false);   // M2n -> L3 row (A)
    AccW t4 = subtree3n(base, 4 * m + 6, L0, L1, red, logs, b, n4);
    bounce_store(L0, t4, 1.f / n4, true);    // M2n -> L0 tr (B)
    if (tid == 0) {                          // r5-fold: zero R5-mid slots
      logs[b * 127 + 114 + 2 * m] = 0.f;
      logs[b * 127 + 115 + 2 * m] = 0.f;
    }
    __syncthreads();
    AccW pb;
    mfma_w16(L3, L0, pb);                    // P2 = M2n@M2n (unnormalized)
    __syncthreads();
    bounce_store(L1, pb, 1.f, true);         // P2 -> L1 tr
    __syncthreads();
    AccW f;
    mfma_w16(L2, L1, f);                     // F = P1@P2
    float tF = bsum16(acc_sumsq(f), red);
    float nF = fmaxf(sqrtf(tF), 1e-12f);
    if (tid == 0) logs[b * 127 + 121 + m] = logf(nF);
    bounce_store(L3, f, 1.f / nF, (m % 2) == 0);
    __syncthreads();
    copy_out(L3, Out + ((size_t)b * 3 + m) * 16384);
  } else {
    // special: two chained r5-special folds.
    if (tid < 128) svf[tid] = sIn[b * 128 + tid];
    loadM(L0, base + 1 * 16384);   // M0[1] odd -> row A
    loadM(L1, base + 2 * 16384);   // M0[2] even -> tr B
    __syncthreads();
    float acc0 = 0.f;              // v1 = svec @ M0[0] (stored tr [h][l])
    if (tid < 128) {
      for (int k8 = 0; k8 < 16; k8++) {
        union { uint4 v; u16 s[8]; } q;
        q.v = *(const uint4*)(base + tid * 128 + k8 * 8);
#pragma unroll
        for (int e = 0; e < 8; e++) acc0 += svf[k8 * 8 + e] * b2f(q.s[e]);
      }
    }
    AccW q1;
    mfma_w16(L0, L1, q1);          // Q1 = M0[1]@M0[2] (unnormalized)
    __syncthreads();
    bounce_store(L0, q1, 1.f, true);  // Q1^T -> L0
    if (tid < 128) svf[128 + tid] = acc0;
    if (tid == 0) {
      logs[b * 127 + 64] = 0.f;
      logs[b * 127 + 65] = 0.f;
    }
    __syncthreads();
    float acc2 = 0.f;              // v2 = v1 @ Q1
    if (tid < 128) {
      for (int l = 0; l < 128; l++) acc2 += svf[128 + l] * b2f(L0[tid * HP + l]);
    }
    float t2s = bsum16((tid < 128) ? acc2 * acc2 : 0.f, red);
    float nv2 = fmaxf(sqrtf(t2s), 1e-12f);
    if (tid == 0) logs[b * 127 + 96] = logf(nv2);
    if (tid < 128) svf[tid] = acc2 / nv2;  // v2n (lower half; svec dead)
    __syncthreads();
    float n0s, n1s, n2s;
    AccW s0 = subtree3n(base, 0, L0, L1, red, logs, b, n0s);  // M2n[0]
    bounce_store(L2, s0, 1.f / n0s, true);  // M2n[0]^T -> L2
    __syncthreads();
    float acc3 = 0.f;              // v3 = v2n @ M2n[0] (unnormalized)
    if (tid < 128) {
      for (int l = 0; l < 128; l++) acc3 += svf[l] * b2f(L2[tid * HP + l]);
    }
    if (tid < 128) svf[128 + tid] = acc3;
    __syncthreads();               // fence L2 reads before overwrite below
    AccW s1 = subtree3n(base, 1, L0, L1, red, logs, b, n1s);  // M2n[1]
    bounce_store(L2, s1, 1.f / n1s, false);  // row -> L2 (A)
    AccW s2 = subtree3n(base, 2, L0, L1, red, logs, b, n2s);  // M2n[2]
    bounce_store(L3, s2, 1.f / n2s, true);   // tr -> L3 (B)
    if (tid == 0) {
      logs[b * 127 + 112] = 0.f;
      logs[b * 127 + 113] = 0.f;
    }
    __syncthreads();
    AccW q2;
    mfma_w16(L2, L3, q2);          // Q2 = M2n[1]@M2n[2] (unnormalized)
    __syncthreads();
    bounce_store(L2, q2, 1.f, true);  // Q2^T -> L2
    __syncthreads();
    float acc4 = 0.f;              // v4 = v3 @ Q2
    if (tid < 128) {
      for (int l = 0; l < 128; l++) acc4 += svf[128 + l] * b2f(L2[tid * HP + l]);
    }
    float t4s = bsum16((tid < 128) ? acc4 * acc4 : 0.f, red);
    float nv4 = fmaxf(sqrtf(t4s), 1e-12f);
    if (tid == 0) logs[b * 127 + 120] = logf(nv4);
    if (tid < 128) sOut[b * 128 + tid] = acc4 / nv4;
  }
}

// ---------------- r7f: R7 + R8 + logits; folded logs -> 1 reduction ----------
__global__ __launch_bounds__(1024, 8) void r7f(const u16* __restrict__ In,
                                               const float* __restrict__ sIn,
                                               const float* __restrict__ logs,
                                               const float* __restrict__ cls,
                                               float* __restrict__ out) {
  __shared__ u16 Ald[128 * HP], Bld[128 * HP];
  __shared__ float svec[128], ovec[128], red[16];
  const int b = blockIdx.x, tid = threadIdx.x;
  if (tid < 128) svec[tid] = sIn[b * 128 + tid];
  loadM(Ald, In + ((size_t)b * 3 + 1) * 16384);   // row-major
  loadM(Bld, In + ((size_t)b * 3 + 2) * 16384);   // transposed
  __syncthreads();
  AccW acc;
  mfma_w16(Ald, Bld, acc);   // C = In1@In2, unnormalized
  // acc0 = svec @ In0 (unnormalized); In0 transposed layout
  const u16* M0p = In + (size_t)b * 3 * 16384;
  float acc0 = 0.f;
  if (tid < 128) {
    for (int k8 = 0; k8 < 16; k8++) {
      union { uint4 v; u16 s[8]; } q;
      q.v = *(const uint4*)(M0p + tid * 128 + k8 * 8);
#pragma unroll
      for (int e = 0; e < 8; e++) acc0 += svec[k8 * 8 + e] * b2f(q.s[e]);
    }
  }
  __syncthreads();  // all Ald/Bld reads done
  bounce_store(Ald, acc, 1.f, true);  // C^T [c][r]
  if (tid < 128) ovec[tid] = acc0;
  __syncthreads();
  // res = (svec@In0) @ C; single log absorbs n0, n1, n2
  float acc2 = 0.f;
  if (tid < 128) {
    for (int r = 0; r < 128; r++) acc2 += ovec[r] * b2f(Ald[tid * HP + r]);
  }
  float tot = bsum16((tid < 128) ? acc2 * acc2 : 0.f, red);
  float n = fmaxf(sqrtf(tot), 1e-12f);
  float lg = logf(n);
  if (tid < 128) svec[tid] = acc2 / n;
  __syncthreads();
  if (tid < 10) {
    float a = 0.f;
    for (int h = 0; h < 128; h++) a += svec[h] * cls[tid * 128 + h];
    float L = lg;
    for (int i = 0; i < 124; i++) L += logs[b * 127 + i];
    out[b * 10 + tid] = a + L;
  }
}

extern "C" void kernel_launch(void* const* d_in, const int* in_sizes, int n_in,
                              void* d_out, int out_size, void* d_ws, size_t ws_size,
                              hipStream_t stream) {
  (void)in_sizes; (void)n_in; (void)out_size; (void)ws_size;
  const float* x     = (const float*)d_in[0];  // (64,256)
  const float* core0 = (const float*)d_in[1];  // (1,2,128)
  const float* cores = (const float*)d_in[2];  // (255,128,2,128)
  const float* cls   = (const float*)d_in[3];  // (10,128)
  float* out = (float*)d_out;
  char* ws = (char*)d_ws;

  // Region A (65 MB): early = T (16.6 MB) + TT (33 MB); later reused as M4.
  constexpr size_t SZ_T  = (size_t)127 * 4 * 16384 * 2;   //  16,646,144
  constexpr size_t SZ_A  = (size_t)64 * 31 * 16384 * 2;   //  65,011,712
  constexpr size_t SZ_M0 = (size_t)64 * 63 * 16384 * 2;   // 132,120,576

  u16*   T    = (u16*)(ws);
  u16*   TT   = (u16*)(ws + SZ_T);
  u16*   M4   = (u16*)(ws);            // aliases T+TT after k2c completes
  u16*   M0   = (u16*)(ws + SZ_A);
  char*  tail0 = ws + SZ_A + SZ_M0;
  float* Gpart = (float*)(tail0);                      // 63*4*256*4 = 258,048
  float* cbuf = (float*)(tail0 + 262144);              // 63*64*16*4 = 258,048
  float* sA   = (float*)(tail0 + 262144 + 262144);
  float* sB   = (float*)(tail0 + 262144 + 262144 + 32768);
  float* logs = (float*)(tail0 + 262144 + 262144 + 65536);

  k1  <<<dim3(127, 2), 1024, 0, stream>>>(cores, T);
  k1b <<<dim3(16, 63), 1024, 0, stream>>>(T, TT);
  k1c <<<dim3(63, 4), 256, 0, stream>>>(TT, Gpart);
  k2ns<<<dim3(127), 128, 0, stream>>>(x, Gpart, core0, cores, T, cbuf, sA, logs);
  k2c <<<dim3(32, 63), 256, 0, stream>>>(TT, cbuf, M0);
  // log slots: 0 special(r1+r2), 1..63 pairs(r1+r2);
  //   tree: 64,65,66..95,112..119 <- 0; writes 96 (sp R3R4 fold), 97..111
  //   (M2 norms), 120 (sp R5R6 fold), 121..123 (M4 norms);
  //   r7f folds its three logs into one local value.
  tree<<<dim3(4, 64), 1024, 0, stream>>>(M0, M4, sA, sB, logs);
  r7f <<<dim3(64), 1024, 0, stream>>>(M4, sB, logs, cls, out);
}